// Round 2
// baseline (1231.592 us; speedup 1.0000x reference)
//
#include <hip/hip_runtime.h>

typedef __attribute__((ext_vector_type(8))) __bf16 bf16x8;
typedef __attribute__((ext_vector_type(4))) float f32x4;
typedef __attribute__((ext_vector_type(8))) unsigned short ushort8;
typedef __attribute__((ext_vector_type(4))) float floatx4;

__device__ __forceinline__ unsigned short f2bf(float f) {
    return __builtin_bit_cast(unsigned short, (__bf16)f);   // RNE via v_cvt
}
__device__ __forceinline__ float bf2f(unsigned short s) {
    return (float)__builtin_bit_cast(__bf16, s);
}
__device__ __forceinline__ float gelu_f(float v) {
    return 0.5f * v * (1.0f + erff(v * 0.70710678118654752440f));
}

// ---- single definition of the swizzled LDS addressing (col in SHORTS) ----
// byte = row*rowBytes + ((col*2) ^ ((row&7)<<4)); bijective per row; for
// 8-element groups at col%8==0 the 16B block stays contiguous (swz bits >=4).
__device__ __forceinline__ char* h1_at(unsigned short* h1, int row, int col) {
    return (char*)h1 + row * 256 + ((col * 2) ^ ((row & 7) << 4));
}
__device__ __forceinline__ char* h2_at(unsigned short* h2, int row, int col) {
    return (char*)h2 + row * 1024 + ((col * 2) ^ ((row & 7) << 4));
}

// B-operand fragment loader: bf16 path (from d_ws) or fp32 fallback
template<bool BF>
__device__ __forceinline__ bf16x8 load_w8(const void* wp, int off) {
    if constexpr (BF) {
        return *(const bf16x8*)((const unsigned short*)wp + off);
    } else {
        const float* p = (const float*)wp + off;
        floatx4 lo = *(const floatx4*)p;
        floatx4 hi = *(const floatx4*)(p + 4);
        union { unsigned short u[8]; bf16x8 v; } pk;
        #pragma unroll
        for (int e = 0; e < 4; ++e) { pk.u[e] = f2bf(lo[e]); pk.u[4 + e] = f2bf(hi[e]); }
        return pk.v;
    }
}

__global__ void prep_kernel(const float* __restrict__ w1, const float* __restrict__ w2,
                            unsigned short* __restrict__ w1b, unsigned short* __restrict__ w2b) {
    int i = blockIdx.x * 256 + threadIdx.x;
    if (i < 512 * 128) w1b[i] = f2bf(w1[i]);
    int j = i - 512 * 128;
    if (j >= 0 && j < 1024 * 512) w2b[j] = f2bf(w2[j]);
}

// 64 rows per block, 256 threads (4 waves). LDS 80KB -> 2 blocks/CU.
template<bool BF>
__global__ __launch_bounds__(256, 2) void fused_mlp(
    const float* __restrict__ x,
    const float* __restrict__ ln0g, const float* __restrict__ ln0b,
    const float* __restrict__ w0,   const float* __restrict__ b0,
    const float* __restrict__ ln1g, const float* __restrict__ ln1b,
    const void*  __restrict__ w1p,  const float* __restrict__ b1,
    const float* __restrict__ ln2g, const float* __restrict__ ln2b,
    const void*  __restrict__ w2p,  const float* __restrict__ b2,
    float* __restrict__ out)
{
    __shared__ alignas(16) unsigned short h1n[64 * 128];
    __shared__ alignas(16) unsigned short h2s[64 * 512];

    const int tid  = threadIdx.x;
    const int lane = tid & 63;
    const int wv   = tid >> 6;
    const long rowbase = (long)blockIdx.x * 64;

    // ---- Phase A: one thread per row, two-pass, no cross-lane ops ----
    if (tid < 64) {
        const int r = tid;
        const long grow = rowbase + r;
        float xv[6], xn[6];
        #pragma unroll
        for (int f = 0; f < 6; ++f) xv[f] = x[grow * 6 + f];
        float mu = 0.f;
        #pragma unroll
        for (int f = 0; f < 6; ++f) mu += xv[f];
        mu *= (1.0f / 6.0f);
        float var = 0.f;
        #pragma unroll
        for (int f = 0; f < 6; ++f) { float d = xv[f] - mu; var += d * d; }
        var *= (1.0f / 6.0f);
        const float rstd = rsqrtf(var + 1e-5f);
        #pragma unroll
        for (int f = 0; f < 6; ++f) xn[f] = (xv[f] - mu) * rstd * ln0g[f] + ln0b[f];

        // pass 1: statistics of the 128 GELU outputs
        float s1 = 0.f, s2 = 0.f;
        #pragma unroll 1
        for (int n = 0; n < 128; ++n) {
            float a = b0[n];
            #pragma unroll
            for (int f = 0; f < 6; ++f) a += xn[f] * w0[n * 6 + f];
            a = gelu_f(a);
            s1 += a; s2 += a * a;
        }
        const float mu1   = s1 * (1.0f / 128.0f);
        const float var1  = s2 * (1.0f / 128.0f) - mu1 * mu1;
        const float rstd1 = rsqrtf(var1 + 1e-5f);

        // pass 2: recompute (identical), normalize, pack to LDS
        #pragma unroll 1
        for (int g = 0; g < 16; ++g) {
            union { unsigned short u[8]; ushort8 v; } pk;
            #pragma unroll
            for (int e = 0; e < 8; ++e) {
                const int n = g * 8 + e;
                float a = b0[n];
                #pragma unroll
                for (int f = 0; f < 6; ++f) a += xn[f] * w0[n * 6 + f];
                a = gelu_f(a);
                pk.u[e] = f2bf((a - mu1) * rstd1 * ln1g[n] + ln1b[n]);
            }
            *(ushort8*)h1_at(h1n, r, g * 8) = pk.v;
        }
    }
    __syncthreads();

    // ---- GEMM1: h1n(64x128) @ w1^T -> GELU -> h2s (bf16) ----
    {
        const int lr = lane & 15;            // A row / B col / D col
        const int lk = (lane >> 4) * 8;      // per-lane k offset
        const int mr = (lane >> 4) * 4;      // D row group
        #pragma unroll 1
        for (int c = 0; c < 2; ++c) {
            const int n0 = wv * 128 + c * 64;
            f32x4 acc[4][4] = {};
            #pragma unroll
            for (int ks = 0; ks < 4; ++ks) {
                const int k0 = ks * 32 + lk;
                bf16x8 af[4], bfv[4];
                #pragma unroll
                for (int i = 0; i < 4; ++i)
                    af[i] = *(const bf16x8*)h1_at(h1n, i * 16 + lr, k0);
                #pragma unroll
                for (int j = 0; j < 4; ++j)
                    bfv[j] = load_w8<BF>(w1p, (n0 + j * 16 + lr) * 128 + k0);
                #pragma unroll
                for (int i = 0; i < 4; ++i)
                    #pragma unroll
                    for (int j = 0; j < 4; ++j)
                        acc[i][j] = __builtin_amdgcn_mfma_f32_16x16x32_bf16(af[i], bfv[j], acc[i][j], 0, 0, 0);
            }
            #pragma unroll
            for (int j = 0; j < 4; ++j) {
                const int n = n0 + j * 16 + lr;
                const float bias = b1[n];
                #pragma unroll
                for (int i = 0; i < 4; ++i)
                    #pragma unroll
                    for (int rr = 0; rr < 4; ++rr) {
                        const int m = i * 16 + mr + rr;
                        *(unsigned short*)h2_at(h2s, m, n) = f2bf(gelu_f(acc[i][j][rr] + bias));
                    }
            }
        }
    }
    __syncthreads();

    // ---- LN over 512: one thread per row, two-pass, in place ----
    if (tid < 64) {
        const int r = tid;
        float s1 = 0.f, s2 = 0.f;
        #pragma unroll 1
        for (int g = 0; g < 64; ++g) {
            ushort8 v = *(const ushort8*)h2_at(h2s, r, g * 8);
            #pragma unroll
            for (int e = 0; e < 8; ++e) { const float f = bf2f(v[e]); s1 += f; s2 += f * f; }
        }
        const float mu   = s1 * (1.0f / 512.0f);
        const float var  = s2 * (1.0f / 512.0f) - mu * mu;
        const float rstd = rsqrtf(var + 1e-5f);
        #pragma unroll 1
        for (int g = 0; g < 64; ++g) {
            char* p = h2_at(h2s, r, g * 8);
            ushort8 v = *(const ushort8*)p;
            union { unsigned short u[8]; ushort8 vv; } pk;
            #pragma unroll
            for (int e = 0; e < 8; ++e) {
                const int n = g * 8 + e;
                pk.u[e] = f2bf((bf2f(v[e]) - mu) * rstd * ln2g[n] + ln2b[n]);
            }
            *(ushort8*)p = pk.vv;
        }
    }
    __syncthreads();

    // ---- GEMM2: h2n(64x512) @ w2^T -> GELU*32 -> out (simple loop) ----
    {
        const int lr = lane & 15;
        const int lk = (lane >> 4) * 8;
        const int mr = (lane >> 4) * 4;
        #pragma unroll 1
        for (int c = 0; c < 4; ++c) {
            const int n0 = wv * 256 + c * 64;
            f32x4 acc[4][4] = {};
            #pragma unroll 1
            for (int ks = 0; ks < 16; ++ks) {
                const int k0 = ks * 32 + lk;
                bf16x8 af[4], bfv[4];
                #pragma unroll
                for (int i = 0; i < 4; ++i)
                    af[i] = *(const bf16x8*)h2_at(h2s, i * 16 + lr, k0);
                #pragma unroll
                for (int j = 0; j < 4; ++j)
                    bfv[j] = load_w8<BF>(w2p, (n0 + j * 16 + lr) * 512 + k0);
                #pragma unroll
                for (int i = 0; i < 4; ++i)
                    #pragma unroll
                    for (int j = 0; j < 4; ++j)
                        acc[i][j] = __builtin_amdgcn_mfma_f32_16x16x32_bf16(af[i], bfv[j], acc[i][j], 0, 0, 0);
            }
            #pragma unroll
            for (int j = 0; j < 4; ++j) {
                const int n = n0 + j * 16 + lr;
                const float bias = b2[n];
                #pragma unroll
                for (int i = 0; i < 4; ++i)
                    #pragma unroll
                    for (int rr = 0; rr < 4; ++rr) {
                        const int m = i * 16 + mr + rr;
                        out[(rowbase + m) * 1024 + n] = gelu_f(acc[i][j][rr] + bias) * 32.0f;
                    }
            }
        }
    }
}

extern "C" void kernel_launch(void* const* d_in, const int* in_sizes, int n_in,
                              void* d_out, int out_size, void* d_ws, size_t ws_size,
                              hipStream_t stream)
{
    const float* x    = (const float*)d_in[0];
    const float* ln0g = (const float*)d_in[1];
    const float* ln0b = (const float*)d_in[2];
    const float* w0   = (const float*)d_in[3];
    const float* b0   = (const float*)d_in[4];
    const float* ln1g = (const float*)d_in[5];
    const float* ln1b = (const float*)d_in[6];
    const float* w1   = (const float*)d_in[7];
    const float* b1   = (const float*)d_in[8];
    const float* ln2g = (const float*)d_in[9];
    const float* ln2b = (const float*)d_in[10];
    const float* w2   = (const float*)d_in[11];
    const float* b2   = (const float*)d_in[12];
    float* out = (float*)d_out;

    const int rows = in_sizes[0] / 6;       // 262144
    const int grid = rows / 64;             // 4096
    const size_t need = (size_t)(512 * 128 + 1024 * 512) * sizeof(unsigned short);

    if (ws_size >= need) {
        unsigned short* w1b = (unsigned short*)d_ws;
        unsigned short* w2b = w1b + 512 * 128;
        prep_kernel<<<dim3((512 * 128 + 1024 * 512 + 255) / 256), dim3(256), 0, stream>>>(w1, w2, w1b, w2b);
        fused_mlp<true><<<dim3(grid), dim3(256), 0, stream>>>(
            x, ln0g, ln0b, w0, b0, ln1g, ln1b, (const void*)w1b, b1,
            ln2g, ln2b, (const void*)w2b, b2, out);
    } else {
        fused_mlp<false><<<dim3(grid), dim3(256), 0, stream>>>(
            x, ln0g, ln0b, w0, b0, ln1g, ln1b, (const void*)w1, b1,
            ln2g, ln2b, (const void*)w2, b2, out);
    }
}